// Round 5
// baseline (454.168 us; speedup 1.0000x reference)
//
#include <hip/hip_runtime.h>

#define T_STEPS 256
#define BATCH   128
#define FEAT    1536            // DH * L = 512 * 3
#define NPAIRS  (T_STEPS * BATCH)
#define SCAN_THREADS 512        // 8 waves -> 2 waves per SIMD (latency hiding)

typedef float vf2 __attribute__((ext_vector_type(2)));   // nontemporal-storable

// ---------------------------------------------------------------------------
// DPP full-wave (64-lane) sum. Result valid in lane 63. All VALU-pipe.
// ---------------------------------------------------------------------------
template <int CTRL, int RMASK>
__device__ __forceinline__ float dpp_add_step(float v) {
    int m = __builtin_amdgcn_update_dpp(0, __float_as_int(v), CTRL, RMASK, 0xF, true);
    return v + __int_as_float(m);
}

__device__ __forceinline__ float wave_reduce63(float v) {
    v = dpp_add_step<0x111, 0xF>(v);   // row_shr:1
    v = dpp_add_step<0x112, 0xF>(v);   // row_shr:2
    v = dpp_add_step<0x114, 0xF>(v);   // row_shr:4
    v = dpp_add_step<0x118, 0xF>(v);   // row_shr:8  -> lanes 15/31/47/63
    v = dpp_add_step<0x142, 0xA>(v);   // row_bcast:15 into rows 1,3
    v = dpp_add_step<0x143, 0xC>(v);   // row_bcast:31 into rows 2,3
    return v;
}

// 1 - sigmoid(x) = 1/(1 + e^x); inf-safe without clamps (rcp(inf)=0).
__device__ __forceinline__ float one_minus_sig(float x) {
    float e = __builtin_amdgcn_exp2f(x * 1.4426950408889634f);
    return __builtin_amdgcn_rcpf(1.0f + e);
}

// tanh(x) = 1 - 2/(1 + e^{2x}); saturates correctly at +/-inf, no clamps.
__device__ __forceinline__ float tanh_fast(float x) {
    float e = __builtin_amdgcn_exp2f(x * 2.8853900817779268f);
    return fmaf(-2.0f, __builtin_amdgcn_rcpf(1.0f + e), 1.0f);
}

// LDS-only barrier: orders ds_write/ds_read across waves WITHOUT draining
// outstanding global stores (keeps HBM store latency off the serial path).
__device__ __forceinline__ void barrier_lds_only() {
    asm volatile("s_waitcnt lgkmcnt(0)\n\ts_barrier" ::: "memory");
}

__device__ __forceinline__ float readlane_f(float v, int lane) {
    return __int_as_float(__builtin_amdgcn_readlane(__float_as_int(v), lane));
}

// ---------------------------------------------------------------------------
// Kernel 1: X[b,t,o] = dot(inputs[t,b,:,:], Wi[o]) + bi[o]
// One block (256 threads) per (t,b) pair. Output transposed (b,t).
// ---------------------------------------------------------------------------
__global__ __launch_bounds__(256) void xdot_kernel(
    const float* __restrict__ x,    // (T*B, 1536)
    const float* __restrict__ Wi,   // (2, 1536)
    const float* __restrict__ bi,   // (2,)
    float* __restrict__ X)          // (B, T) float2
{
    const int p    = blockIdx.x;           // t*BATCH + b
    const int tid  = threadIdx.x;
    const int wid  = tid >> 6;
    const int lane = tid & 63;

    __shared__ float red[8];               // 4 waves x 2 partials

    const float* xp = x + (size_t)p * FEAT;
    const float4 v4 = ((const float4*)xp)[tid];
    const float2 v2 = ((const float2*)(xp + 1024))[tid];

    const float4 w04 = ((const float4*)Wi)[tid];
    const float2 w02 = ((const float2*)(Wi + 1024))[tid];
    const float4 w14 = ((const float4*)(Wi + FEAT))[tid];
    const float2 w12 = ((const float2*)(Wi + FEAT + 1024))[tid];

    float a0 = v4.x * w04.x + v4.y * w04.y + v4.z * w04.z + v4.w * w04.w
             + v2.x * w02.x + v2.y * w02.y;
    float a1 = v4.x * w14.x + v4.y * w14.y + v4.z * w14.z + v4.w * w14.w
             + v2.x * w12.x + v2.y * w12.y;

    a0 = wave_reduce63(a0);
    a1 = wave_reduce63(a1);
    if (lane == 63) {
        red[wid * 2]     = a0;
        red[wid * 2 + 1] = a1;
    }
    __syncthreads();
    if (tid == 0) {
        const float s0 = red[0] + red[2] + red[4] + red[6] + bi[0];
        const float s1 = red[1] + red[3] + red[5] + red[7] + bi[1];
        const int b = p & (BATCH - 1);
        const int t = p >> 7;                    // p / BATCH
        ((float2*)X)[b * T_STEPS + t] = make_float2(s0, s1);
    }
}

// ---------------------------------------------------------------------------
// Kernel 2: sequential scan. One 512-thread block (8 waves) per batch elem:
// 2 waves/SIMD so one wave's issue fills the other's LDS/barrier/trans
// latency. Thread t owns state elems {2t,2t+1} (float2) and {1024+t} (float).
// Gate transcendentals de-duplicated: lanes 0-3 each compute one gate column
// (one exp2 + one rcp per wave), broadcast via readlane.
// ---------------------------------------------------------------------------
__global__ __launch_bounds__(SCAN_THREADS) void scan_kernel(
    const float* __restrict__ h0,
    const float* __restrict__ c0,
    const float* __restrict__ Wr, const float* __restrict__ br,
    const float* __restrict__ Wc, const float* __restrict__ bc,
    const float* __restrict__ X,    // (B, T) float2
    float* __restrict__ outs,       // (T*B, 1536)
    float* __restrict__ hT,         // (B, 1536)
    float* __restrict__ cT)         // (B, 1536)
{
    const int b    = blockIdx.x;
    const int tid  = threadIdx.x;
    const int wid  = tid >> 6;      // 0..7
    const int lane = tid & 63;
    const int col  = lane & 3;      // gate column this lane helps compute

    __shared__ float  red[2][32];   // double-buffered: 8 waves x float4
    __shared__ float2 Xsh[T_STEPS];

    if (tid < T_STEPS) Xsh[tid] = ((const float2*)X)[b * T_STEPS + tid];

    // weight fragments: float2 over [0,1024), float over [1024,1536)
    const float2 wr0_2 = ((const float2*)Wr)[tid];
    const float  wr0_1 = Wr[1024 + tid];
    const float2 wr1_2 = ((const float2*)(Wr + FEAT))[tid];
    const float  wr1_1 = (Wr + FEAT)[1024 + tid];
    const float2 wc0_2 = ((const float2*)Wc)[tid];
    const float  wc0_1 = Wc[1024 + tid];
    const float2 wc1_2 = ((const float2*)(Wc + FEAT))[tid];
    const float  wc1_1 = (Wc + FEAT)[1024 + tid];

    // per-lane gate bias: col {0:Hc+br0, 1:Hh+br1, 2:Cc+bc0, 3:Ch+bc1}
    const float bias_c = (col == 0) ? br[0] : (col == 1) ? br[1]
                       : (col == 2) ? bc[0] : bc[1];

    const float* h0b = h0 + (size_t)b * FEAT;
    const float* c0b = c0 + (size_t)b * FEAT;
    float2 h2 = ((const float2*)h0b)[tid];
    float  h1 = h0b[1024 + tid];
    float2 c2 = ((const float2*)c0b)[tid];
    float  c1 = c0b[1024 + tid];

    float* op = outs + (size_t)b * FEAT;
    const size_t OSTRIDE = (size_t)BATCH * FEAT;

    __syncthreads();   // Xsh visible (one-time)

    auto step = [&](float* buf, int t) {
        const float2 Xv = Xsh[t];

        float pHc = h2.x * wr0_2.x + h2.y * wr0_2.y + h1 * wr0_1;
        float pHh = h2.x * wr1_2.x + h2.y * wr1_2.y + h1 * wr1_1;
        float pCc = c2.x * wc0_2.x + c2.y * wc0_2.y + c1 * wc0_1;
        float pCh = c2.x * wc1_2.x + c2.y * wc1_2.y + c1 * wc1_1;

        pHc = wave_reduce63(pHc);
        pHh = wave_reduce63(pHh);
        pCc = wave_reduce63(pCc);
        pCh = wave_reduce63(pCh);

        if (lane == 63) {
            *(float4*)&buf[wid * 4] = make_float4(pHc, pHh, pCc, pCh);
        }
        barrier_lds_only();

        // col-parallel gate: lane sums its column over the 8 wave partials
        float s = bias_c;
#pragma unroll
        for (int w = 0; w < 8; ++w) s += buf[w * 4 + col];
        float g = one_minus_sig(s);
        // col0: Ac = g*Xc ; col3: Ah = g*Xh ; cols 1,2 unscaled (Sh, Sc)
        const float m = (col == 0) ? Xv.x : (col == 3) ? Xv.y : 1.0f;
        g *= m;

        const float Ac = readlane_f(g, 0);
        const float Sh = readlane_f(g, 1);
        const float Sc = readlane_f(g, 2);
        const float Ah = readlane_f(g, 3);

        h2.x = tanh_fast(fmaf(Sh, h2.x, Ah));
        h2.y = tanh_fast(fmaf(Sh, h2.y, Ah));
        h1   = tanh_fast(fmaf(Sh, h1,   Ah));
        c2.x = tanh_fast(fmaf(Sc, c2.x, Ac));
        c2.y = tanh_fast(fmaf(Sc, c2.y, Ac));
        c1   = tanh_fast(fmaf(Sc, c1,   Ac));

        // outs[t, b, :] = ht (fire-and-forget, nontemporal; never drained
        // inside the loop)
        vf2 hv; hv.x = h2.x; hv.y = h2.y;
        __builtin_nontemporal_store(hv, (vf2*)op + tid);
        __builtin_nontemporal_store(h1, op + 1024 + tid);
        op += OSTRIDE;
    };

#pragma unroll 1
    for (int t = 0; t < T_STEPS; t += 2) {
        step(red[0], t);
        step(red[1], t + 1);
    }

    float* hp = hT + (size_t)b * FEAT;
    ((float2*)hp)[tid] = h2;
    hp[1024 + tid]     = h1;
    float* cp = cT + (size_t)b * FEAT;
    ((float2*)cp)[tid] = c2;
    cp[1024 + tid]     = c1;
}

extern "C" void kernel_launch(void* const* d_in, const int* in_sizes, int n_in,
                              void* d_out, int out_size, void* d_ws, size_t ws_size,
                              hipStream_t stream) {
    const float* inputs = (const float*)d_in[0];
    const float* h0     = (const float*)d_in[1];
    const float* c0     = (const float*)d_in[2];
    const float* Wr     = (const float*)d_in[3];
    const float* br     = (const float*)d_in[4];
    const float* Wc     = (const float*)d_in[5];
    const float* bc     = (const float*)d_in[6];
    const float* Wi     = (const float*)d_in[7];
    const float* bi     = (const float*)d_in[8];

    float* out = (float*)d_out;
    float* X   = (float*)d_ws;               // 256 KiB: (B, T) float2

    float* outs = out;                                        // (T,B,1536)
    float* hT   = out + (size_t)NPAIRS * FEAT;                // (B,1536)
    float* cT   = hT + (size_t)BATCH * FEAT;                  // (B,1536)

    xdot_kernel<<<NPAIRS, 256, 0, stream>>>(inputs, Wi, bi, X);
    scan_kernel<<<BATCH, SCAN_THREADS, 0, stream>>>(h0, c0, Wr, br, Wc, bc, X,
                                                    outs, hT, cT);
}